// Round 1
// baseline (308.495 us; speedup 1.0000x reference)
//
#include <hip/hip_runtime.h>

#define NB 64
#define NC 768
#define NN 576          // 24*24
#define NF4 144         // NN/4
#define NCHUNK 8
#define CSZ 96          // NC / NCHUNK
#define SPLIT 192       // NN / 3

// ---- workspace layout (bytes) ----
#define OFF_HM   0ull                         // double [2][NB][NCHUNK][NN]
#define SZ_HM    (2ull*NB*NCHUNK*NN*8ull)
#define OFF_GID  (OFF_HM + SZ_HM)             // uint  [2][NB][NN]
#define SZ_GID   (2ull*NB*NN*4ull)
#define OFF_GSUM (OFF_GID + SZ_GID)           // float [2][NB][3][NC]   (g-major => coalesced in k4)
#define SZ_GSUM  (2ull*NB*3ull*NC*4ull)
#define OFF_PB   (OFF_GSUM + SZ_GSUM)         // double [NB]

// Kernel 1: per-(input,b,c-chunk) partial heatmap sums over C, f64 accumulate.
// 576 threads = 144 float4-columns x 4 c-offsets; LDS-reduce the 4 c-offsets.
__global__ __launch_bounds__(576) void k_heat(const float* __restrict__ f1,
                                              const float* __restrict__ f2,
                                              double* __restrict__ hm) {
    int bx    = blockIdx.x;            // 2*NB*NCHUNK
    int chunk = bx & (NCHUNK - 1);
    int b     = (bx >> 3) & (NB - 1);
    int inp   = bx >> 9;
    const float* f = inp ? f2 : f1;
    const float4* plane = (const float4*)(f + (size_t)b * NC * NN);  // [NC][NF4]

    int t  = threadIdx.x;
    int n4 = t % NF4;                  // float4 column
    int cc = t / NF4;                  // 0..3 c-offset
    double a0 = 0, a1 = 0, a2 = 0, a3 = 0;
    int c0 = chunk * CSZ + cc;
    #pragma unroll 4
    for (int i = 0; i < CSZ / 4; ++i) {            // 24 rows per thread
        float4 v = plane[(size_t)(c0 + 4 * i) * NF4 + n4];
        a0 += (double)v.x; a1 += (double)v.y; a2 += (double)v.z; a3 += (double)v.w;
    }
    __shared__ double red[4][NN];
    red[cc][n4 * 4 + 0] = a0;
    red[cc][n4 * 4 + 1] = a1;
    red[cc][n4 * 4 + 2] = a2;
    red[cc][n4 * 4 + 3] = a3;
    __syncthreads();
    double s = red[0][t] + red[1][t] + red[2][t] + red[3][t];   // thread t == position n=t
    hm[((size_t)(inp * NB + b) * NCHUNK + chunk) * NN + t] = s;
}

// Kernel 2: per-(input,b): finish heatmap, rank each position (stable desc), emit group id.
__global__ __launch_bounds__(576) void k_rank(const double* __restrict__ hm,
                                              unsigned* __restrict__ gid) {
    int bx = blockIdx.x;               // inp*NB + b  (128 blocks)
    int t  = threadIdx.x;
    const double* p = hm + (size_t)bx * NCHUNK * NN;
    double h = 0;
    #pragma unroll
    for (int ch = 0; ch < NCHUNK; ++ch) h += p[(size_t)ch * NN + t];
    __shared__ double hs[NN];
    hs[t] = h;
    __syncthreads();
    int cnt = 0;
    for (int j = 0; j < NN; ++j) {     // uniform j => LDS broadcast (free)
        double hj = hs[j];
        cnt += (hj > h) ? 1 : ((hj == h && j < t) ? 1 : 0);
    }
    unsigned g = (cnt >= 2 * SPLIT) ? 2u : ((cnt >= SPLIT) ? 1u : 0u);
    gid[(size_t)bx * NN + t] = g;
}

__device__ __forceinline__ void acc3(float v, unsigned g,
                                     float& a0, float& a1, float& a2) {
    a0 += (g == 0u) ? v : 0.0f;
    a1 += (g == 1u) ? v : 0.0f;
    a2 += (g == 2u) ? v : 0.0f;
}

// Kernel 3: group sums per (input,b,c,g). Wave-per-row; 12 rows per wave.
// Group ids are c-invariant -> preloaded per lane once.
#define CG 48
__global__ __launch_bounds__(256) void k_gsum(const float* __restrict__ f1,
                                              const float* __restrict__ f2,
                                              const unsigned* __restrict__ gid,
                                              float* __restrict__ gsum) {
    int bx  = blockIdx.x;              // 2*NB*(NC/CG) = 2048
    int cgi = bx & 15;
    int b   = (bx >> 4) & (NB - 1);
    int inp = bx >> 10;
    const float* f = inp ? f2 : f1;
    const float4* plane = (const float4*)(f + (size_t)b * NC * NN);
    const uint4* g4 = (const uint4*)(gid + (size_t)(inp * NB + b) * NN);
    float* out = gsum + (size_t)(inp * NB + b) * (3 * NC);

    int t = threadIdx.x;
    int w = t >> 6;                    // wave 0..3
    int l = t & 63;

    uint4 ga = g4[l];                  // n = 4l .. 4l+3
    uint4 gb = g4[l + 64];             // n = 256+4l ..
    uint4 gc = make_uint4(0, 0, 0, 0);
    if (l < 16) gc = g4[l + 128];      // n = 512+4l ..

    for (int i = 0; i < CG / 4; ++i) {
        int c = cgi * CG + 4 * i + w;
        const float4* row = plane + (size_t)c * NF4;
        float4 v0 = row[l];
        float4 v1 = row[l + 64];
        float4 v2 = make_float4(0.f, 0.f, 0.f, 0.f);
        if (l < 16) v2 = row[l + 128];

        float a0 = 0.f, a1 = 0.f, a2 = 0.f;
        acc3(v0.x, ga.x, a0, a1, a2); acc3(v0.y, ga.y, a0, a1, a2);
        acc3(v0.z, ga.z, a0, a1, a2); acc3(v0.w, ga.w, a0, a1, a2);
        acc3(v1.x, gb.x, a0, a1, a2); acc3(v1.y, gb.y, a0, a1, a2);
        acc3(v1.z, gb.z, a0, a1, a2); acc3(v1.w, gb.w, a0, a1, a2);
        acc3(v2.x, gc.x, a0, a1, a2); acc3(v2.y, gc.y, a0, a1, a2);
        acc3(v2.z, gc.z, a0, a1, a2); acc3(v2.w, gc.w, a0, a1, a2);

        #pragma unroll
        for (int m = 32; m; m >>= 1) {
            a0 += __shfl_xor(a0, m);
            a1 += __shfl_xor(a1, m);
            a2 += __shfl_xor(a2, m);
        }
        if (l == 0) {
            out[0 * NC + c] = a0;
            out[1 * NC + c] = a1;
            out[2 * NC + c] = a2;
        }
    }
}

// Kernel 4: per-b: means (/192), L2 norms (f64), MSE partial (f64).
__global__ __launch_bounds__(256) void k_mse(const float* __restrict__ gsum,
                                             double* __restrict__ pb) {
    int b = blockIdx.x;
    int t = threadIdx.x;
    int w = t >> 6, l = t & 63;
    const float* s1 = gsum + (size_t)b * (3 * NC);
    const float* s2 = gsum + (size_t)(NB + b) * (3 * NC);

    double v1[9], v2[9];
    double q1 = 0, q2 = 0;
    #pragma unroll
    for (int k = 0; k < 9; ++k) {       // 3*NC = 2304 = 256*9
        int i = t + 256 * k;
        v1[k] = (double)s1[i] * (1.0 / 192.0);
        v2[k] = (double)s2[i] * (1.0 / 192.0);
        q1 += v1[k] * v1[k];
        q2 += v2[k] * v2[k];
    }
    #pragma unroll
    for (int m = 32; m; m >>= 1) { q1 += __shfl_xor(q1, m); q2 += __shfl_xor(q2, m); }
    __shared__ double red1[4], red2[4];
    if (l == 0) { red1[w] = q1; red2[w] = q2; }
    __syncthreads();
    q1 = red1[0] + red1[1] + red1[2] + red1[3];
    q2 = red2[0] + red2[1] + red2[2] + red2[3];
    double inv1 = 1.0 / fmax(sqrt(q1), 1e-12);
    double inv2 = 1.0 / fmax(sqrt(q2), 1e-12);

    double acc = 0;
    #pragma unroll
    for (int k = 0; k < 9; ++k) {
        double d = v1[k] * inv1 - v2[k] * inv2;
        acc += d * d;
    }
    #pragma unroll
    for (int m = 32; m; m >>= 1) acc += __shfl_xor(acc, m);
    __syncthreads();
    if (l == 0) red1[w] = acc;
    __syncthreads();
    if (t == 0) pb[b] = red1[0] + red1[1] + red1[2] + red1[3];
}

// Kernel 5: final scalar.
__global__ __launch_bounds__(64) void k_final(const double* __restrict__ pb,
                                              float* __restrict__ out) {
    int l = threadIdx.x;
    double v = pb[l];
    #pragma unroll
    for (int m = 32; m; m >>= 1) v += __shfl_xor(v, m);
    if (l == 0) out[0] = (float)(v / ((double)NB * 3.0 * (double)NC));
}

extern "C" void kernel_launch(void* const* d_in, const int* in_sizes, int n_in,
                              void* d_out, int out_size, void* d_ws, size_t ws_size,
                              hipStream_t stream) {
    (void)in_sizes; (void)n_in; (void)out_size; (void)ws_size;
    const float* f1 = (const float*)d_in[0];
    const float* f2 = (const float*)d_in[1];
    // d_in[2]=logit_scale, d_in[3]=weights unused; d_in[4]=blocks fixed at 3.
    float* out = (float*)d_out;
    char* ws = (char*)d_ws;

    double*   hm   = (double*)(ws + OFF_HM);
    unsigned* gid  = (unsigned*)(ws + OFF_GID);
    float*    gsum = (float*)(ws + OFF_GSUM);
    double*   pb   = (double*)(ws + OFF_PB);

    k_heat <<<2 * NB * NCHUNK, 576, 0, stream>>>(f1, f2, hm);
    k_rank <<<2 * NB,          576, 0, stream>>>(hm, gid);
    k_gsum <<<2 * NB * (NC/CG),256, 0, stream>>>(f1, f2, gid, gsum);
    k_mse  <<<NB,              256, 0, stream>>>(gsum, pb);
    k_final<<<1,               64,  0, stream>>>(pb, out);
}

// Round 2
// 304.785 us; speedup vs baseline: 1.0122x; 1.0122x over previous
//
#include <hip/hip_runtime.h>

#define NB 64
#define NC 768
#define NN 576          // 24*24
#define NF4 144         // NN/4

#define HCH 16          // k_heat chunks (48 rows each)
#define HROWS 48
#define GCH 8           // k_gsum chunks (96 rows each)
#define GROWS 96

// ---- workspace layout (bytes) ----
#define OFF_HM   0ull                          // double [2*NB][HCH][NN]  = 9.44 MB
#define SZ_HM    (2ull*NB*HCH*NN*8ull)
#define OFF_GID  (OFF_HM + SZ_HM)              // uchar  [2*NB][NN]       = 72 KB
#define SZ_GID   (2ull*NB*NN)
#define OFF_GP   (OFF_GID + SZ_GID)            // float  [2*NB][NC][3][4] = 4.72 MB
#define SZ_GP    (2ull*NB*NC*12ull*4ull)
#define OFF_PB   (OFF_GP + SZ_GP)              // double [NB]

// Kernel 1: heatmap partial sums. 192 threads (3 waves, no LDS), thread owns
// columns {t, t+192, t+384}; 18 independent loads in flight (6-row groups).
// All loads are base+immediate-offset (row/col offsets compile-time).
__global__ __launch_bounds__(192, 6) void k_heat(const float* __restrict__ f1,
                                                 const float* __restrict__ f2,
                                                 double* __restrict__ hm) {
    int bx    = blockIdx.x;            // 2*NB*HCH = 2048
    int chunk = bx & (HCH - 1);
    int b     = (bx >> 4) & (NB - 1);
    int inp   = bx >> 10;
    const float* f = (inp ? f2 : f1) + (size_t)b * NC * NN + (size_t)chunk * HROWS * NN;
    int t = threadIdx.x;
    double d0 = 0, d1 = 0, d2 = 0;
    for (int r = 0; r < HROWS; r += 6) {
        float v[18];
        #pragma unroll
        for (int rr = 0; rr < 6; ++rr) {
            const float* row = f + (size_t)(r + rr) * NN + t;
            v[rr * 3 + 0] = row[0];
            v[rr * 3 + 1] = row[192];
            v[rr * 3 + 2] = row[384];
        }
        #pragma unroll
        for (int rr = 0; rr < 6; ++rr) {
            d0 += (double)v[rr * 3 + 0];
            d1 += (double)v[rr * 3 + 1];
            d2 += (double)v[rr * 3 + 2];
        }
    }
    double* o = hm + ((size_t)(inp * NB + b) * HCH + chunk) * NN;
    o[t] = d0; o[t + 192] = d1; o[t + 384] = d2;
}

// Kernel 2: finish heatmap (f64), rank positions (stable desc), emit packed gid byte.
__global__ __launch_bounds__(576) void k_rank(const double* __restrict__ hm,
                                              unsigned char* __restrict__ gid8) {
    int bx = blockIdx.x;               // inp*NB + b  (128 blocks)
    int t  = threadIdx.x;
    const double* p = hm + (size_t)bx * HCH * NN;
    double h = 0;
    #pragma unroll
    for (int ch = 0; ch < HCH; ++ch) h += p[(size_t)ch * NN + t];
    __shared__ double hs[NN];
    hs[t] = h;
    __syncthreads();
    int cnt = 0;
    for (int j = 0; j < NN; ++j) {     // uniform j => LDS broadcast
        double hj = hs[j];
        cnt += (hj > h) ? 1 : ((hj == h && j < t) ? 1 : 0);
    }
    gid8[(size_t)bx * NN + t] = (cnt >= 384) ? 2 : ((cnt >= 192) ? 1 : 0);
}

// Kernel 3: group sums. 16 lanes per c-row, 4 rows per wave, 9 independent
// float4 loads per row, selection via packed gid bytes (subtract trick),
// 2 shfl_xor per accumulator -> 4 partials per (c,g); k_mse finishes.
__global__ __launch_bounds__(256, 4) void k_gsum(const float* __restrict__ f1,
                                                 const float* __restrict__ f2,
                                                 const unsigned* __restrict__ gidw,
                                                 float* __restrict__ gp) {
    int bx    = blockIdx.x;            // 2*NB*GCH = 1024
    int chunk = bx & (GCH - 1);
    int b     = (bx >> 3) & (NB - 1);
    int inp   = bx >> 9;
    const float4* plane = (const float4*)((inp ? f2 : f1) + (size_t)b * NC * NN);
    int t = threadIdx.x;
    int w = t >> 6, l = t & 63;
    int sub = l & 15, rr = l >> 4;

    unsigned g[9];
    const unsigned* gw = gidw + (size_t)(inp * NB + b) * NF4;
    #pragma unroll
    for (int k = 0; k < 9; ++k) g[k] = gw[sub + 16 * k];

    float* out = gp + (size_t)(inp * NB + b) * NC * 12;
    int cbase = chunk * GROWS + w * 4 + rr;
    #pragma unroll 2
    for (int i = 0; i < 6; ++i) {
        int c = cbase + i * 16;
        const float4* row = plane + (size_t)c * NF4 + sub;
        float4 v[9];
        #pragma unroll
        for (int k = 0; k < 9; ++k) v[k] = row[16 * k];
        float sa = 0.f, s1 = 0.f, s2 = 0.f;
        #pragma unroll
        for (int k = 0; k < 9; ++k) {
            unsigned gwk = g[k];
            float x;
            unsigned gg;
            x = v[k].x; gg = gwk & 0xffu;         sa += x; s1 += (gg >= 1u) ? x : 0.f; s2 += (gg == 2u) ? x : 0.f;
            x = v[k].y; gg = (gwk >> 8) & 0xffu;  sa += x; s1 += (gg >= 1u) ? x : 0.f; s2 += (gg == 2u) ? x : 0.f;
            x = v[k].z; gg = (gwk >> 16) & 0xffu; sa += x; s1 += (gg >= 1u) ? x : 0.f; s2 += (gg == 2u) ? x : 0.f;
            x = v[k].w; gg = gwk >> 24;           sa += x; s1 += (gg >= 1u) ? x : 0.f; s2 += (gg == 2u) ? x : 0.f;
        }
        sa += __shfl_xor(sa, 4); s1 += __shfl_xor(s1, 4); s2 += __shfl_xor(s2, 4);
        sa += __shfl_xor(sa, 8); s1 += __shfl_xor(s1, 8); s2 += __shfl_xor(s2, 8);
        if (sub < 4) {
            float* o = out + (size_t)c * 12;
            o[0 * 4 + sub] = sa - s1;      // group 0
            o[1 * 4 + sub] = s1 - s2;      // group 1
            o[2 * 4 + sub] = s2;           // group 2
        }
    }
}

// Kernel 4: per-b: finish part sums, means (/192), L2 norms (f64), MSE partial.
__global__ __launch_bounds__(256) void k_mse(const float* __restrict__ gp,
                                             double* __restrict__ pb) {
    int b = blockIdx.x;
    int t = threadIdx.x;
    int w = t >> 6, l = t & 63;
    const float4* s1 = (const float4*)(gp + (size_t)b * NC * 12);
    const float4* s2 = (const float4*)(gp + (size_t)(NB + b) * NC * 12);

    double v1[9], v2[9];
    double q1 = 0, q2 = 0;
    #pragma unroll
    for (int k = 0; k < 9; ++k) {       // 2304 entries = 256*9; entry e = c*3+g
        int e = t + 256 * k;
        float4 a = s1[e], c4 = s2[e];
        v1[k] = ((double)a.x + (double)a.y + (double)a.z + (double)a.w) * (1.0 / 192.0);
        v2[k] = ((double)c4.x + (double)c4.y + (double)c4.z + (double)c4.w) * (1.0 / 192.0);
        q1 += v1[k] * v1[k];
        q2 += v2[k] * v2[k];
    }
    #pragma unroll
    for (int m = 32; m; m >>= 1) { q1 += __shfl_xor(q1, m); q2 += __shfl_xor(q2, m); }
    __shared__ double red1[4], red2[4];
    if (l == 0) { red1[w] = q1; red2[w] = q2; }
    __syncthreads();
    q1 = red1[0] + red1[1] + red1[2] + red1[3];
    q2 = red2[0] + red2[1] + red2[2] + red2[3];
    double inv1 = 1.0 / fmax(sqrt(q1), 1e-12);
    double inv2 = 1.0 / fmax(sqrt(q2), 1e-12);

    double acc = 0;
    #pragma unroll
    for (int k = 0; k < 9; ++k) {
        double d = v1[k] * inv1 - v2[k] * inv2;
        acc += d * d;
    }
    #pragma unroll
    for (int m = 32; m; m >>= 1) acc += __shfl_xor(acc, m);
    __syncthreads();
    if (l == 0) red1[w] = acc;
    __syncthreads();
    if (t == 0) pb[b] = red1[0] + red1[1] + red1[2] + red1[3];
}

// Kernel 5: final scalar.
__global__ __launch_bounds__(64) void k_final(const double* __restrict__ pb,
                                              float* __restrict__ out) {
    int l = threadIdx.x;
    double v = pb[l];
    #pragma unroll
    for (int m = 32; m; m >>= 1) v += __shfl_xor(v, m);
    if (l == 0) out[0] = (float)(v / ((double)NB * 3.0 * (double)NC));
}

extern "C" void kernel_launch(void* const* d_in, const int* in_sizes, int n_in,
                              void* d_out, int out_size, void* d_ws, size_t ws_size,
                              hipStream_t stream) {
    (void)in_sizes; (void)n_in; (void)out_size; (void)ws_size;
    const float* f1 = (const float*)d_in[0];
    const float* f2 = (const float*)d_in[1];
    float* out = (float*)d_out;
    char* ws = (char*)d_ws;

    double*        hm   = (double*)(ws + OFF_HM);
    unsigned char* gid8 = (unsigned char*)(ws + OFF_GID);
    float*         gp   = (float*)(ws + OFF_GP);
    double*        pb   = (double*)(ws + OFF_PB);

    k_heat <<<2 * NB * HCH, 192, 0, stream>>>(f1, f2, hm);
    k_rank <<<2 * NB,       576, 0, stream>>>(hm, gid8);
    k_gsum <<<2 * NB * GCH, 256, 0, stream>>>(f1, f2, (const unsigned*)gid8, gp);
    k_mse  <<<NB,           256, 0, stream>>>(gp, pb);
    k_final<<<1,            64,  0, stream>>>(pb, out);
}